// Round 1
// baseline (658.842 us; speedup 1.0000x reference)
//
#include <hip/hip_runtime.h>

#define NENT 100000
#define DIM 200
#define ODIM 2000
#define KERN 9
#define OCH 32
#define LOUT 1992
#define FCLEN 63744
#define BSZ 512
#define EPSV 1e-5f
#define KPAD 224

typedef float f32x4 __attribute__((ext_vector_type(4)));
typedef short short8 __attribute__((ext_vector_type(8)));
typedef __bf16 bf16x8 __attribute__((ext_vector_type(8)));
typedef unsigned int uint4v __attribute__((ext_vector_type(4)));
typedef unsigned int uint2v __attribute__((ext_vector_type(2)));

__device__ __forceinline__ unsigned short f2bf(float f) {
  unsigned int u = __float_as_uint(f);
  return (unsigned short)((u + 0x7fffu + ((u >> 16) & 1u)) >> 16);
}

__device__ __forceinline__ float wredf(float v) {
#pragma unroll
  for (int o = 32; o > 0; o >>= 1) v += __shfl_down(v, o, 64);
  return v;
}

// ---------- zero bias ----------
__global__ void k_init(float* bias) {
  int t = threadIdx.x;
  if (t < DIM) bias[t] = 0.f;
}

// ---------- BN0 stats -> affine coeffs ----------
__global__ void k_bn0(const float* __restrict__ E, const int* __restrict__ e1,
                      const float* __restrict__ g, const float* __restrict__ b,
                      float* __restrict__ A, float* __restrict__ Bc) {
  int f = blockIdx.x, ln = threadIdx.x;
  float s1 = 0.f, s2 = 0.f;
  for (int i = ln; i < BSZ; i += 64) {
    float v = E[(long)e1[i] * DIM + f];
    s1 += v; s2 += v * v;
  }
  s1 = wredf(s1); s2 = wredf(s2);
  if (ln == 0) {
    float m = s1 / BSZ;
    float var = s2 / BSZ - m * m;
    float a = g[f] * rsqrtf(var + EPSV);
    A[f] = a; Bc[f] = b[f] - m * a;
  }
}

// ---------- x1 = bn0(E[e1]) @ e_W  (512 x 2000) ----------
__global__ void __launch_bounds__(256) k_mm1(
    const float* __restrict__ E, const int* __restrict__ e1,
    const float* __restrict__ eW, const float* __restrict__ A,
    const float* __restrict__ Bc, float* __restrict__ x1) {
  __shared__ float xs[8][DIM];
  int t = threadIdx.x, b0 = blockIdx.x * 8;
  for (int idx = t; idx < 8 * DIM; idx += 256) {
    int bi = idx / DIM, f = idx % DIM;
    xs[bi][f] = E[(long)e1[b0 + bi] * DIM + f] * A[f] + Bc[f];
  }
  __syncthreads();
  float acc[8][8];
#pragma unroll
  for (int bi = 0; bi < 8; bi++)
#pragma unroll
    for (int m = 0; m < 8; m++) acc[bi][m] = 0.f;
  for (int k = 0; k < DIM; k++) {
    float ew[8];
#pragma unroll
    for (int m = 0; m < 8; m++) {
      int j = t + 256 * m;
      ew[m] = (j < ODIM) ? eW[(long)k * ODIM + j] : 0.f;
    }
#pragma unroll
    for (int bi = 0; bi < 8; bi++) {
      float xv = xs[bi][k];
#pragma unroll
      for (int m = 0; m < 8; m++) acc[bi][m] += xv * ew[m];
    }
  }
#pragma unroll
  for (int bi = 0; bi < 8; bi++)
#pragma unroll
    for (int m = 0; m < 8; m++) {
      int j = t + 256 * m;
      if (j < ODIM) x1[(long)(b0 + bi) * ODIM + j] = acc[bi][m];
    }
}

// ---------- conv (per-sample filters) -> bf16 + per-block BN1 partial stats ----------
__global__ void __launch_bounds__(256) k_conv(
    const float* __restrict__ x1, const float* __restrict__ R,
    const int* __restrict__ ridx, unsigned short* __restrict__ convb,
    float* __restrict__ part) {
  __shared__ float xs[ODIM];
  __shared__ float kr[OCH * KERN];
  __shared__ float wr4[4][64];
  int t = threadIdx.x, b = blockIdx.x;
  for (int i = t; i < ODIM; i += 256) xs[i] = x1[(long)b * ODIM + i];
  for (int i = t; i < OCH * KERN; i += 256) kr[i] = R[(long)ridx[b] * (OCH * KERN) + i];
  __syncthreads();
  int l0 = t * 8;
  bool act = (t < 249);  // 249*8 = 1992 outputs per channel
  float w[16];
  if (act) {
#pragma unroll
    for (int i = 0; i < 16; i++) w[i] = xs[l0 + i];
  }
  int wv = t >> 6, ln = t & 63;
  for (int o = 0; o < OCH; o++) {
    float s1 = 0.f, s2 = 0.f;
    if (act) {
      float kk[KERN];
#pragma unroll
      for (int k = 0; k < KERN; k++) kk[k] = kr[o * KERN + k];
      float cb[8];
#pragma unroll
      for (int j = 0; j < 8; j++) {
        float c = 0.f;
#pragma unroll
        for (int k = 0; k < KERN; k++) c += kk[k] * w[j + k];
        cb[j] = c; s1 += c; s2 += c * c;
      }
      uint4v pk;
#pragma unroll
      for (int i = 0; i < 4; i++)
        pk[i] = (unsigned)f2bf(cb[2 * i]) | ((unsigned)f2bf(cb[2 * i + 1]) << 16);
      *(uint4v*)(convb + (long)b * FCLEN + o * LOUT + l0) = pk;
    }
    s1 = wredf(s1); s2 = wredf(s2);
    if (ln == 0) { wr4[wv][o] = s1; wr4[wv][o + 32] = s2; }
  }
  __syncthreads();
  if (t < 64) part[(long)b * 64 + t] = wr4[0][t] + wr4[1][t] + wr4[2][t] + wr4[3][t];
}

// ---------- finalize BN1 -> a[o], c[o] ----------
__global__ void k_bn1fin(const float* __restrict__ part, const float* __restrict__ g,
                         const float* __restrict__ b, float* __restrict__ a,
                         float* __restrict__ c) {
  __shared__ float sm[4][64];
  __shared__ float tot[64];
  int t = threadIdx.x;
  int si = t >> 6, st = t & 63;
  float s = 0.f;
  for (int i = si; i < BSZ; i += 4) s += part[(long)i * 64 + st];
  sm[si][st] = s;
  __syncthreads();
  if (t < 64) tot[t] = sm[0][t] + sm[1][t] + sm[2][t] + sm[3][t];
  __syncthreads();
  if (t < OCH) {
    float N = (float)BSZ * LOUT;
    float m = tot[t] / N;
    float var = tot[t + 32] / N - m * m;
    float av = g[t] * rsqrtf(var + EPSV);
    a[t] = av; c[t] = b[t] - m * av;
  }
}

// ---------- fcW fp32 -> bf16 scaled by a[o]; bias[d] += c[o]*rowsum ----------
__global__ void __launch_bounds__(256) k_fcw(
    const float* __restrict__ fcW, const float* __restrict__ a,
    const float* __restrict__ c, unsigned short* __restrict__ fcWb,
    float* __restrict__ bias) {
  int d = blockIdx.x, o = blockIdx.y, t = threadIdx.x;
  const float* src = fcW + (long)d * FCLEN + o * LOUT;
  unsigned short* dst = fcWb + (long)d * FCLEN + o * LOUT;
  float ao = a[o];
  float s = 0.f;
  if (t < 249) {
    float v[8];
#pragma unroll
    for (int j = 0; j < 8; j++) { v[j] = src[t * 8 + j]; s += v[j]; }
    uint4v pk;
#pragma unroll
    for (int i = 0; i < 4; i++)
      pk[i] = (unsigned)f2bf(v[2 * i] * ao) | ((unsigned)f2bf(v[2 * i + 1] * ao) << 16);
    *(uint4v*)(dst + t * 8) = pk;
  }
  s = wredf(s);
  __shared__ float sm[4];
  if ((t & 63) == 0) sm[t >> 6] = s;
  __syncthreads();
  if (t == 0) atomicAdd(bias + d, c[o] * (sm[0] + sm[1] + sm[2] + sm[3]));
}

// ---------- y init to bias ----------
__global__ void k_yinit(const float* __restrict__ bias, float* __restrict__ y) {
  int i = blockIdx.x * 256 + threadIdx.x;  // 512*200 = 102400 = 400*256
  y[i] = bias[i % DIM];
}

// ---------- fc GEMM: y += conv(bf16) @ fcWb^T, 128x128 tile, BK=96, split-K ----------
__global__ void __launch_bounds__(256) k_gemm_fc(
    const unsigned short* __restrict__ convb, const unsigned short* __restrict__ fcWb,
    float* __restrict__ y) {
  __shared__ unsigned short lA[128 * 104];
  __shared__ unsigned short lB[128 * 104];
  int t = threadIdx.x;
  int b0 = blockIdx.x * 128, n0 = blockIdx.y * 128, z = blockIdx.z;
  int s0 = (664 * z) / 32, s1 = (664 * (z + 1)) / 32;  // 664 = 63744/96 steps
  int w = t >> 6, lane = t & 63, lm = lane & 15, quad = lane >> 4;
  int mq = (w >> 1) * 64, nq = (w & 1) * 64;
  f32x4 acc[4][4];
#pragma unroll
  for (int mi = 0; mi < 4; mi++)
#pragma unroll
    for (int ni = 0; ni < 4; ni++) acc[mi][ni] = (f32x4){0.f, 0.f, 0.f, 0.f};
  for (int st = s0; st < s1; st++) {
    long kc = (long)st * 96;
    __syncthreads();
#pragma unroll
    for (int i = 0; i < 6; i++) {  // 128 rows * 12 chunks = 1536 = 6*256
      int cc = t + 256 * i;
      int row = cc / 12, c8 = cc % 12;
      *(uint4v*)&lA[row * 104 + c8 * 8] =
          *(const uint4v*)&convb[(long)(b0 + row) * FCLEN + kc + c8 * 8];
      uint4v bv = (uint4v){0u, 0u, 0u, 0u};
      int nr = n0 + row;
      if (nr < DIM) bv = *(const uint4v*)&fcWb[(long)nr * FCLEN + kc + c8 * 8];
      *(uint4v*)&lB[row * 104 + c8 * 8] = bv;
    }
    __syncthreads();
#pragma unroll
    for (int ks = 0; ks < 96; ks += 32) {
      short8 af[4], bfr[4];
#pragma unroll
      for (int i2 = 0; i2 < 4; i2++) {
        af[i2] = *(const short8*)&lA[(mq + i2 * 16 + lm) * 104 + ks + quad * 8];
        bfr[i2] = *(const short8*)&lB[(nq + i2 * 16 + lm) * 104 + ks + quad * 8];
      }
#pragma unroll
      for (int mi = 0; mi < 4; mi++)
#pragma unroll
        for (int ni = 0; ni < 4; ni++)
          acc[mi][ni] = __builtin_amdgcn_mfma_f32_16x16x32_bf16(
              __builtin_bit_cast(bf16x8, af[mi]), __builtin_bit_cast(bf16x8, bfr[ni]),
              acc[mi][ni], 0, 0, 0);
    }
  }
#pragma unroll
  for (int mi = 0; mi < 4; mi++)
#pragma unroll
    for (int ni = 0; ni < 4; ni++)
#pragma unroll
      for (int r = 0; r < 4; r++) {
        int gm = b0 + mq + mi * 16 + quad * 4 + r;
        int gn = n0 + nq + ni * 16 + lm;
        if (gn < DIM) atomicAdd(&y[(long)gm * DIM + gn], acc[mi][ni][r]);
      }
}

// ---------- BN2 + tanh -> xt bf16 (512 x 224, zero-padded) ----------
__global__ void k_bn2(const float* __restrict__ y, const float* __restrict__ g,
                      const float* __restrict__ b, unsigned short* __restrict__ xt) {
  int d = blockIdx.x, ln = threadIdx.x;
  if (d >= DIM) {
    for (int i = ln; i < BSZ; i += 64) xt[(long)i * KPAD + d] = 0;
    return;
  }
  float v[8];
  float s1 = 0.f, s2 = 0.f;
#pragma unroll
  for (int j = 0; j < 8; j++) {
    v[j] = y[(long)(ln + 64 * j) * DIM + d];
    s1 += v[j]; s2 += v[j] * v[j];
  }
  s1 = wredf(s1); s2 = wredf(s2);
  s1 = __shfl(s1, 0, 64); s2 = __shfl(s2, 0, 64);
  float m = s1 / BSZ, var = s2 / BSZ - m * m;
  float a = g[d] * rsqrtf(var + EPSV), c = b[d] - m * a;
#pragma unroll
  for (int j = 0; j < 8; j++)
    xt[(long)(ln + 64 * j) * KPAD + d] = f2bf(tanhf(v[j] * a + c));
}

// ---------- final GEMM: out = sigmoid(xt @ E^T); M=512 whole, N-tile=64 ----------
__global__ void __launch_bounds__(256) k_gemmf(
    const unsigned short* __restrict__ xt, const float* __restrict__ E,
    float* __restrict__ out) {
  __shared__ unsigned short lB[64 * 232];
  int t = threadIdx.x;
  long e0 = (long)blockIdx.x * 64;
  // stage B: 64 E-rows, inline fp32->bf16, K padded 200->224 (zeros)
#pragma unroll
  for (int i = 0; i < 13; i++) {
    int cc = t + 256 * i;
    if (cc < 3200) {  // 64 rows * 50 float4-chunks
      int row = cc / 50, c4 = cc % 50;
      long e = e0 + row;
      f32x4 v = (f32x4){0.f, 0.f, 0.f, 0.f};
      if (e < NENT) v = *(const f32x4*)&E[e * DIM + c4 * 4];
      uint2v pk;
      pk[0] = (unsigned)f2bf(v[0]) | ((unsigned)f2bf(v[1]) << 16);
      pk[1] = (unsigned)f2bf(v[2]) | ((unsigned)f2bf(v[3]) << 16);
      *(uint2v*)&lB[row * 232 + c4 * 4] = pk;
    }
  }
  {  // zero pad cols 200..231
    int row = t >> 2, cp = t & 3;
    uint4v z = (uint4v){0u, 0u, 0u, 0u};
    *(uint4v*)&lB[row * 232 + 200 + cp * 8] = z;
  }
  __syncthreads();
  int w = t >> 6, lane = t & 63, lm = lane & 15, quad = lane >> 4;
  int r0 = w * 128;
  f32x4 acc[8][4];
#pragma unroll
  for (int mi = 0; mi < 8; mi++)
#pragma unroll
    for (int ni = 0; ni < 4; ni++) acc[mi][ni] = (f32x4){0.f, 0.f, 0.f, 0.f};
#pragma unroll
  for (int kk = 0; kk < 7; kk++) {
    int k0 = kk * 32;
    short8 bfr[4];
#pragma unroll
    for (int ni = 0; ni < 4; ni++)
      bfr[ni] = *(const short8*)&lB[(ni * 16 + lm) * 232 + k0 + quad * 8];
#pragma unroll
    for (int mi = 0; mi < 8; mi++) {
      short8 af = *(const short8*)&xt[(long)(r0 + mi * 16 + lm) * KPAD + k0 + quad * 8];
#pragma unroll
      for (int ni = 0; ni < 4; ni++)
        acc[mi][ni] = __builtin_amdgcn_mfma_f32_16x16x32_bf16(
            __builtin_bit_cast(bf16x8, af), __builtin_bit_cast(bf16x8, bfr[ni]),
            acc[mi][ni], 0, 0, 0);
    }
  }
#pragma unroll
  for (int mi = 0; mi < 8; mi++)
#pragma unroll
    for (int ni = 0; ni < 4; ni++)
#pragma unroll
      for (int r = 0; r < 4; r++) {
        int gb = r0 + mi * 16 + quad * 4 + r;
        long ge = e0 + ni * 16 + lm;
        if (ge < NENT) {
          float x = acc[mi][ni][r];
          out[(long)gb * NENT + ge] = 1.f / (1.f + __expf(-x));
        }
      }
}

extern "C" void kernel_launch(void* const* d_in, const int* in_sizes, int n_in,
                              void* d_out, int out_size, void* d_ws, size_t ws_size,
                              hipStream_t stream) {
  const float* E = (const float*)d_in[0];
  const float* R = (const float*)d_in[1];
  const float* eW = (const float*)d_in[2];
  const float* fcW = (const float*)d_in[3];
  const float* bn0g = (const float*)d_in[4];
  const float* bn0b = (const float*)d_in[5];
  const float* bn1g = (const float*)d_in[6];
  const float* bn1b = (const float*)d_in[7];
  const float* bn2g = (const float*)d_in[8];
  const float* bn2b = (const float*)d_in[9];
  const int* e1 = (const int*)d_in[10];
  const int* ridx = (const int*)d_in[11];
  float* outp = (float*)d_out;

  char* p = (char*)d_ws;
  size_t off = 0;
  auto alloc = [&](size_t bytes) -> char* {
    char* r = p + off;
    off = (off + bytes + 255) & ~(size_t)255;
    return r;
  };
  float* x1 = (float*)alloc((size_t)BSZ * ODIM * 4);
  unsigned short* convb = (unsigned short*)alloc((size_t)BSZ * FCLEN * 2);
  unsigned short* fcWb = (unsigned short*)alloc((size_t)DIM * FCLEN * 2);
  float* y = (float*)alloc((size_t)BSZ * DIM * 4);
  unsigned short* xt = (unsigned short*)alloc((size_t)BSZ * KPAD * 2);
  float* bn0A = (float*)alloc(DIM * 4);
  float* bn0B = (float*)alloc(DIM * 4);
  float* part = (float*)alloc((size_t)BSZ * 64 * 4);
  float* bn1a = (float*)alloc(OCH * 4);
  float* bn1c = (float*)alloc(OCH * 4);
  float* bias = (float*)alloc(DIM * 4);

  k_init<<<1, 256, 0, stream>>>(bias);
  k_bn0<<<DIM, 64, 0, stream>>>(E, e1, bn0g, bn0b, bn0A, bn0B);
  k_mm1<<<64, 256, 0, stream>>>(E, e1, eW, bn0A, bn0B, x1);
  k_conv<<<BSZ, 256, 0, stream>>>(x1, R, ridx, convb, part);
  k_bn1fin<<<1, 256, 0, stream>>>(part, bn1g, bn1b, bn1a, bn1c);
  k_fcw<<<dim3(DIM, OCH), 256, 0, stream>>>(fcW, bn1a, bn1c, fcWb, bias);
  k_yinit<<<400, 256, 0, stream>>>(bias, y);
  k_gemm_fc<<<dim3(4, 2, 32), 256, 0, stream>>>(convb, fcWb, y);
  k_bn2<<<KPAD, 64, 0, stream>>>(y, bn2g, bn2b, xt);
  k_gemmf<<<dim3((NENT + 63) / 64), 256, 0, stream>>>(xt, E, outp);
}

// Round 2
// 561.106 us; speedup vs baseline: 1.1742x; 1.1742x over previous
//
#include <hip/hip_runtime.h>

#define NENT 100000
#define DIM 200
#define ODIM 2000
#define KERN 9
#define OCH 32
#define LOUT 1992
#define FCLEN 63744
#define BSZ 512
#define EPSV 1e-5f
#define KPAD 224

typedef float f32x4 __attribute__((ext_vector_type(4)));
typedef short short8 __attribute__((ext_vector_type(8)));
typedef __bf16 bf16x8 __attribute__((ext_vector_type(8)));
typedef unsigned int uint4v __attribute__((ext_vector_type(4)));
typedef unsigned int uint2v __attribute__((ext_vector_type(2)));

__device__ __forceinline__ unsigned short f2bf(float f) {
  unsigned int u = __float_as_uint(f);
  return (unsigned short)((u + 0x7fffu + ((u >> 16) & 1u)) >> 16);
}

__device__ __forceinline__ float wredf(float v) {
#pragma unroll
  for (int o = 32; o > 0; o >>= 1) v += __shfl_down(v, o, 64);
  return v;
}

// ---------- zero bias ----------
__global__ void k_init(float* bias) {
  int t = threadIdx.x;
  if (t < DIM) bias[t] = 0.f;
}

// ---------- BN0 stats -> affine coeffs ----------
__global__ void k_bn0(const float* __restrict__ E, const int* __restrict__ e1,
                      const float* __restrict__ g, const float* __restrict__ b,
                      float* __restrict__ A, float* __restrict__ Bc) {
  int f = blockIdx.x, ln = threadIdx.x;
  float s1 = 0.f, s2 = 0.f;
  for (int i = ln; i < BSZ; i += 64) {
    float v = E[(long)e1[i] * DIM + f];
    s1 += v; s2 += v * v;
  }
  s1 = wredf(s1); s2 = wredf(s2);
  if (ln == 0) {
    float m = s1 / BSZ;
    float var = s2 / BSZ - m * m;
    float a = g[f] * rsqrtf(var + EPSV);
    A[f] = a; Bc[f] = b[f] - m * a;
  }
}

// ---------- x1 = bn0(E[e1]) @ e_W  (512 x 2000), 16x128 tiles ----------
// 512 blocks (2/CU), each thread 4 rows x 2 cols; LDS x-tile is wave-broadcast.
__global__ void __launch_bounds__(256) k_mm1(
    const float* __restrict__ E, const int* __restrict__ e1,
    const float* __restrict__ eW, const float* __restrict__ A,
    const float* __restrict__ Bc, float* __restrict__ x1) {
  __shared__ float xs[16][DIM];  // 12.8 KB
  int t = threadIdx.x;
  int b0 = blockIdx.x * 16, n0 = blockIdx.y * 128;
  for (int idx = t; idx < 16 * DIM; idx += 256) {
    int bi = idx / DIM, f = idx % DIM;
    xs[bi][f] = E[(long)e1[b0 + bi] * DIM + f] * A[f] + Bc[f];
  }
  __syncthreads();
  int lane = t & 63, w = t >> 6;
  int j0 = n0 + lane, j1 = j0 + 64;
  int r0 = w * 4;
  bool c0 = (j0 < ODIM), c1 = (j1 < ODIM);
  float acc[4][2];
#pragma unroll
  for (int r = 0; r < 4; r++) { acc[r][0] = 0.f; acc[r][1] = 0.f; }
  for (int k = 0; k < DIM; k += 4) {
    f32x4 xr[4];
#pragma unroll
    for (int r = 0; r < 4; r++) xr[r] = *(const f32x4*)&xs[r0 + r][k];
#pragma unroll
    for (int kk = 0; kk < 4; kk++) {
      float e0v = c0 ? eW[(long)(k + kk) * ODIM + j0] : 0.f;
      float e1v = c1 ? eW[(long)(k + kk) * ODIM + j1] : 0.f;
#pragma unroll
      for (int r = 0; r < 4; r++) {
        acc[r][0] += xr[r][kk] * e0v;
        acc[r][1] += xr[r][kk] * e1v;
      }
    }
  }
#pragma unroll
  for (int r = 0; r < 4; r++) {
    long base = (long)(b0 + r0 + r) * ODIM;
    if (c0) x1[base + j0] = acc[r][0];
    if (c1) x1[base + j1] = acc[r][1];
  }
}

// ---------- conv (per-sample filters) -> bf16 + per-block BN1 partial stats ----------
__global__ void __launch_bounds__(256) k_conv(
    const float* __restrict__ x1, const float* __restrict__ R,
    const int* __restrict__ ridx, unsigned short* __restrict__ convb,
    float* __restrict__ part) {
  __shared__ float xs[ODIM];
  __shared__ float kr[OCH * KERN];
  __shared__ float wr4[4][64];
  int t = threadIdx.x, b = blockIdx.x;
  for (int i = t; i < ODIM; i += 256) xs[i] = x1[(long)b * ODIM + i];
  for (int i = t; i < OCH * KERN; i += 256) kr[i] = R[(long)ridx[b] * (OCH * KERN) + i];
  __syncthreads();
  int l0 = t * 8;
  bool act = (t < 249);  // 249*8 = 1992 outputs per channel
  float w[16];
  if (act) {
#pragma unroll
    for (int i = 0; i < 16; i++) w[i] = xs[l0 + i];
  }
  int wv = t >> 6, ln = t & 63;
  for (int o = 0; o < OCH; o++) {
    float s1 = 0.f, s2 = 0.f;
    if (act) {
      float kk[KERN];
#pragma unroll
      for (int k = 0; k < KERN; k++) kk[k] = kr[o * KERN + k];
      float cb[8];
#pragma unroll
      for (int j = 0; j < 8; j++) {
        float c = 0.f;
#pragma unroll
        for (int k = 0; k < KERN; k++) c += kk[k] * w[j + k];
        cb[j] = c; s1 += c; s2 += c * c;
      }
      uint4v pk;
#pragma unroll
      for (int i = 0; i < 4; i++)
        pk[i] = (unsigned)f2bf(cb[2 * i]) | ((unsigned)f2bf(cb[2 * i + 1]) << 16);
      *(uint4v*)(convb + (long)b * FCLEN + o * LOUT + l0) = pk;
    }
    s1 = wredf(s1); s2 = wredf(s2);
    if (ln == 0) { wr4[wv][o] = s1; wr4[wv][o + 32] = s2; }
  }
  __syncthreads();
  if (t < 64) part[(long)b * 64 + t] = wr4[0][t] + wr4[1][t] + wr4[2][t] + wr4[3][t];
}

// ---------- finalize BN1 -> a[o], c[o] ----------
__global__ void k_bn1fin(const float* __restrict__ part, const float* __restrict__ g,
                         const float* __restrict__ b, float* __restrict__ a,
                         float* __restrict__ c) {
  __shared__ float sm[4][64];
  __shared__ float tot[64];
  int t = threadIdx.x;
  int si = t >> 6, st = t & 63;
  float s = 0.f;
  for (int i = si; i < BSZ; i += 4) s += part[(long)i * 64 + st];
  sm[si][st] = s;
  __syncthreads();
  if (t < 64) tot[t] = sm[0][t] + sm[1][t] + sm[2][t] + sm[3][t];
  __syncthreads();
  if (t < OCH) {
    float N = (float)BSZ * LOUT;
    float m = tot[t] / N;
    float var = tot[t + 32] / N - m * m;
    float av = g[t] * rsqrtf(var + EPSV);
    a[t] = av; c[t] = b[t] - m * av;
  }
}

// ---------- fcW fp32 -> bf16 scaled by a[o]; bias[d] += c[o]*rowsum ----------
__global__ void __launch_bounds__(256) k_fcw(
    const float* __restrict__ fcW, const float* __restrict__ a,
    const float* __restrict__ c, unsigned short* __restrict__ fcWb,
    float* __restrict__ bias) {
  int d = blockIdx.x, o = blockIdx.y, t = threadIdx.x;
  const float* src = fcW + (long)d * FCLEN + o * LOUT;
  unsigned short* dst = fcWb + (long)d * FCLEN + o * LOUT;
  float ao = a[o];
  float s = 0.f;
  if (t < 249) {
    float v[8];
#pragma unroll
    for (int j = 0; j < 8; j++) { v[j] = src[t * 8 + j]; s += v[j]; }
    uint4v pk;
#pragma unroll
    for (int i = 0; i < 4; i++)
      pk[i] = (unsigned)f2bf(v[2 * i] * ao) | ((unsigned)f2bf(v[2 * i + 1] * ao) << 16);
    *(uint4v*)(dst + t * 8) = pk;
  }
  s = wredf(s);
  __shared__ float sm[4];
  if ((t & 63) == 0) sm[t >> 6] = s;
  __syncthreads();
  if (t == 0) atomicAdd(bias + d, c[o] * (sm[0] + sm[1] + sm[2] + sm[3]));
}

// ---------- fc GEMM: ypart[z] = conv(bf16) @ fcWb^T slice, 128x128 tile, BK=96 ----------
__global__ void __launch_bounds__(256) k_gemm_fc(
    const unsigned short* __restrict__ convb, const unsigned short* __restrict__ fcWb,
    float* __restrict__ ypart) {
  __shared__ unsigned short lA[128 * 104];
  __shared__ unsigned short lB[128 * 104];
  int t = threadIdx.x;
  int b0 = blockIdx.x * 128, n0 = blockIdx.y * 128, z = blockIdx.z;
  int s0 = (664 * z) / 32, s1 = (664 * (z + 1)) / 32;  // 664 = 63744/96 steps
  int w = t >> 6, lane = t & 63, lm = lane & 15, quad = lane >> 4;
  int mq = (w >> 1) * 64, nq = (w & 1) * 64;
  f32x4 acc[4][4];
#pragma unroll
  for (int mi = 0; mi < 4; mi++)
#pragma unroll
    for (int ni = 0; ni < 4; ni++) acc[mi][ni] = (f32x4){0.f, 0.f, 0.f, 0.f};
  for (int st = s0; st < s1; st++) {
    long kc = (long)st * 96;
    __syncthreads();
#pragma unroll
    for (int i = 0; i < 6; i++) {  // 128 rows * 12 chunks = 1536 = 6*256
      int cc = t + 256 * i;
      int row = cc / 12, c8 = cc % 12;
      *(uint4v*)&lA[row * 104 + c8 * 8] =
          *(const uint4v*)&convb[(long)(b0 + row) * FCLEN + kc + c8 * 8];
      uint4v bv = (uint4v){0u, 0u, 0u, 0u};
      int nr = n0 + row;
      if (nr < DIM) bv = *(const uint4v*)&fcWb[(long)nr * FCLEN + kc + c8 * 8];
      *(uint4v*)&lB[row * 104 + c8 * 8] = bv;
    }
    __syncthreads();
#pragma unroll
    for (int ks = 0; ks < 96; ks += 32) {
      short8 af[4], bfr[4];
#pragma unroll
      for (int i2 = 0; i2 < 4; i2++) {
        af[i2] = *(const short8*)&lA[(mq + i2 * 16 + lm) * 104 + ks + quad * 8];
        bfr[i2] = *(const short8*)&lB[(nq + i2 * 16 + lm) * 104 + ks + quad * 8];
      }
#pragma unroll
      for (int mi = 0; mi < 4; mi++)
#pragma unroll
        for (int ni = 0; ni < 4; ni++)
          acc[mi][ni] = __builtin_amdgcn_mfma_f32_16x16x32_bf16(
              __builtin_bit_cast(bf16x8, af[mi]), __builtin_bit_cast(bf16x8, bfr[ni]),
              acc[mi][ni], 0, 0, 0);
    }
  }
  // write split-K partials (N padded to 256); no atomics
#pragma unroll
  for (int mi = 0; mi < 4; mi++)
#pragma unroll
    for (int ni = 0; ni < 4; ni++)
#pragma unroll
      for (int r = 0; r < 4; r++) {
        int gm = b0 + mq + mi * 16 + quad * 4 + r;
        int gn = n0 + nq + ni * 16 + lm;
        ypart[((long)z * BSZ + gm) * 256 + gn] = acc[mi][ni][r];
      }
}

// ---------- reduce split-K partials + bias -> y[512][200] ----------
__global__ void __launch_bounds__(256) k_yred(
    const float* __restrict__ ypart, const float* __restrict__ bias,
    float* __restrict__ y) {
  int i = blockIdx.x * 256 + threadIdx.x;  // 102400 total
  int m = i / DIM, d = i % DIM;
  float s = bias[d];
#pragma unroll 8
  for (int z = 0; z < 32; z++) s += ypart[((long)z * BSZ + m) * 256 + d];
  y[(long)m * DIM + d] = s;
}

// ---------- BN2 + tanh -> xt bf16 (512 x 224, zero-padded) ----------
__global__ void k_bn2(const float* __restrict__ y, const float* __restrict__ g,
                      const float* __restrict__ b, unsigned short* __restrict__ xt) {
  int d = blockIdx.x, ln = threadIdx.x;
  if (d >= DIM) {
    for (int i = ln; i < BSZ; i += 64) xt[(long)i * KPAD + d] = 0;
    return;
  }
  float v[8];
  float s1 = 0.f, s2 = 0.f;
#pragma unroll
  for (int j = 0; j < 8; j++) {
    v[j] = y[(long)(ln + 64 * j) * DIM + d];
    s1 += v[j]; s2 += v[j] * v[j];
  }
  s1 = wredf(s1); s2 = wredf(s2);
  s1 = __shfl(s1, 0, 64); s2 = __shfl(s2, 0, 64);
  float m = s1 / BSZ, var = s2 / BSZ - m * m;
  float a = g[d] * rsqrtf(var + EPSV), c = b[d] - m * a;
#pragma unroll
  for (int j = 0; j < 8; j++)
    xt[(long)(ln + 64 * j) * KPAD + d] = f2bf(tanhf(v[j] * a + c));
}

// ---------- final GEMM: out = sigmoid(xt @ E^T); M=512 whole, N-tile=64 ----------
__global__ void __launch_bounds__(256) k_gemmf(
    const unsigned short* __restrict__ xt, const float* __restrict__ E,
    float* __restrict__ out) {
  __shared__ unsigned short lB[64 * 232];
  int t = threadIdx.x;
  long e0 = (long)blockIdx.x * 64;
  // stage B: 64 E-rows, inline fp32->bf16, K padded 200->224 (zeros)
#pragma unroll
  for (int i = 0; i < 13; i++) {
    int cc = t + 256 * i;
    if (cc < 3200) {  // 64 rows * 50 float4-chunks
      int row = cc / 50, c4 = cc % 50;
      long e = e0 + row;
      f32x4 v = (f32x4){0.f, 0.f, 0.f, 0.f};
      if (e < NENT) v = *(const f32x4*)&E[e * DIM + c4 * 4];
      uint2v pk;
      pk[0] = (unsigned)f2bf(v[0]) | ((unsigned)f2bf(v[1]) << 16);
      pk[1] = (unsigned)f2bf(v[2]) | ((unsigned)f2bf(v[3]) << 16);
      *(uint2v*)&lB[row * 232 + c4 * 4] = pk;
    }
  }
  {  // zero pad cols 200..231
    int row = t >> 2, cp = t & 3;
    uint4v zz = (uint4v){0u, 0u, 0u, 0u};
    *(uint4v*)&lB[row * 232 + 200 + cp * 8] = zz;
  }
  __syncthreads();
  int w = t >> 6, lane = t & 63, lm = lane & 15, quad = lane >> 4;
  int r0 = w * 128;
  f32x4 acc[8][4];
#pragma unroll
  for (int mi = 0; mi < 8; mi++)
#pragma unroll
    for (int ni = 0; ni < 4; ni++) acc[mi][ni] = (f32x4){0.f, 0.f, 0.f, 0.f};
#pragma unroll
  for (int kk = 0; kk < 7; kk++) {
    int k0 = kk * 32;
    short8 bfr[4];
#pragma unroll
    for (int ni = 0; ni < 4; ni++)
      bfr[ni] = *(const short8*)&lB[(ni * 16 + lm) * 232 + k0 + quad * 8];
#pragma unroll
    for (int mi = 0; mi < 8; mi++) {
      short8 af = *(const short8*)&xt[(long)(r0 + mi * 16 + lm) * KPAD + k0 + quad * 8];
#pragma unroll
      for (int ni = 0; ni < 4; ni++)
        acc[mi][ni] = __builtin_amdgcn_mfma_f32_16x16x32_bf16(
            __builtin_bit_cast(bf16x8, af), __builtin_bit_cast(bf16x8, bfr[ni]),
            acc[mi][ni], 0, 0, 0);
    }
  }
#pragma unroll
  for (int mi = 0; mi < 8; mi++)
#pragma unroll
    for (int ni = 0; ni < 4; ni++)
#pragma unroll
      for (int r = 0; r < 4; r++) {
        int gb = r0 + mi * 16 + quad * 4 + r;
        long ge = e0 + ni * 16 + lm;
        if (ge < NENT) {
          float x = acc[mi][ni][r];
          out[(long)gb * NENT + ge] = 1.f / (1.f + __expf(-x));
        }
      }
}

extern "C" void kernel_launch(void* const* d_in, const int* in_sizes, int n_in,
                              void* d_out, int out_size, void* d_ws, size_t ws_size,
                              hipStream_t stream) {
  const float* E = (const float*)d_in[0];
  const float* R = (const float*)d_in[1];
  const float* eW = (const float*)d_in[2];
  const float* fcW = (const float*)d_in[3];
  const float* bn0g = (const float*)d_in[4];
  const float* bn0b = (const float*)d_in[5];
  const float* bn1g = (const float*)d_in[6];
  const float* bn1b = (const float*)d_in[7];
  const float* bn2g = (const float*)d_in[8];
  const float* bn2b = (const float*)d_in[9];
  const int* e1 = (const int*)d_in[10];
  const int* ridx = (const int*)d_in[11];
  float* outp = (float*)d_out;

  char* p = (char*)d_ws;
  size_t off = 0;
  auto alloc = [&](size_t bytes) -> char* {
    char* r = p + off;
    off = (off + bytes + 255) & ~(size_t)255;
    return r;
  };
  float* x1 = (float*)alloc((size_t)BSZ * ODIM * 4);
  unsigned short* convb = (unsigned short*)alloc((size_t)BSZ * FCLEN * 2);
  unsigned short* fcWb = (unsigned short*)alloc((size_t)DIM * FCLEN * 2);
  float* ypart = (float*)alloc((size_t)32 * BSZ * 256 * 4);
  float* y = (float*)alloc((size_t)BSZ * DIM * 4);
  unsigned short* xt = (unsigned short*)alloc((size_t)BSZ * KPAD * 2);
  float* bn0A = (float*)alloc(DIM * 4);
  float* bn0B = (float*)alloc(DIM * 4);
  float* part = (float*)alloc((size_t)BSZ * 64 * 4);
  float* bn1a = (float*)alloc(OCH * 4);
  float* bn1c = (float*)alloc(OCH * 4);
  float* bias = (float*)alloc(DIM * 4);

  k_init<<<1, 256, 0, stream>>>(bias);
  k_bn0<<<DIM, 64, 0, stream>>>(E, e1, bn0g, bn0b, bn0A, bn0B);
  k_mm1<<<dim3(32, 16), 256, 0, stream>>>(E, e1, eW, bn0A, bn0B, x1);
  k_conv<<<BSZ, 256, 0, stream>>>(x1, R, ridx, convb, part);
  k_bn1fin<<<1, 256, 0, stream>>>(part, bn1g, bn1b, bn1a, bn1c);
  k_fcw<<<dim3(DIM, OCH), 256, 0, stream>>>(fcW, bn1a, bn1c, fcWb, bias);
  k_gemm_fc<<<dim3(4, 2, 32), 256, 0, stream>>>(convb, fcWb, ypart);
  k_yred<<<400, 256, 0, stream>>>(ypart, bias, y);
  k_bn2<<<KPAD, 64, 0, stream>>>(y, bn2g, bn2b, xt);
  k_gemmf<<<dim3((NENT + 63) / 64), 256, 0, stream>>>(xt, E, outp);
}